// Round 3
// baseline (285.538 us; speedup 1.0000x reference)
//
#include <hip/hip_runtime.h>

typedef float v2f __attribute__((ext_vector_type(2)));

// ==========================================================================
// Compile-time Clebsch-Gordan (real basis) table generation.
// Mirrors the reference Python exactly: _cg_complex, _u_matrix, _real_cg.
// ==========================================================================
namespace cg {

constexpr double FACT[16] = {
  1.0, 1.0, 2.0, 6.0, 24.0, 120.0, 720.0, 5040.0, 40320.0, 362880.0,
  3628800.0, 39916800.0, 479001600.0, 6227020800.0, 87178291200.0,
  1307674368000.0 };

constexpr double csqrt_(double x){
  if (x <= 0.0) return 0.0;
  double xx = x, g = 1.0;
  while (xx >= 256.0)      { xx *= (1.0/256.0); g *= 16.0;       }
  while (xx >= 4.0)        { xx *= 0.25;        g *= 2.0;        }
  while (xx < (1.0/256.0)) { xx *= 256.0;       g *= (1.0/16.0); }
  while (xx < 1.0)         { xx *= 4.0;         g *= 0.5;        }
  double s = 1.5;
  for (int i = 0; i < 10; ++i) s = 0.5*(s + xx/s);
  return g*s;
}

constexpr double cg_complex(int j1,int m1,int j2,int m2,int j3,int m3){
  if (m1+m2 != m3) return 0.0;
  int dj = j1-j2; if (dj < 0) dj = -dj;
  if (j3 < dj || j3 > j1+j2) return 0.0;
  if (m1<-j1||m1>j1||m2<-j2||m2>j2||m3<-j3||m3>j3) return 0.0;
  double pre = csqrt_((2.0*j3+1.0)*FACT[j1+j2-j3]*FACT[j1-j2+j3]*FACT[-j1+j2+j3]/FACT[j1+j2+j3+1]);
  pre *= csqrt_(FACT[j1+m1]*FACT[j1-m1]*FACT[j2+m2]*FACT[j2-m2]*FACT[j3+m3]*FACT[j3-m3]);
  double s = 0.0;
  for (int k = 0; k <= j1+j2+j3; ++k){
    int t1=j1+j2-j3-k, t2=j1-m1-k, t3=j2+m2-k, t4=j3-j2+m1+k, t5=j3-j1-m2+k;
    if (t1<0||t2<0||t3<0||t4<0||t5<0) continue;
    double term = 1.0/(FACT[k]*FACT[t1]*FACT[t2]*FACT[t3]*FACT[t4]*FACT[t5]);
    s += (k & 1) ? -term : term;
  }
  return pre*s;
}

struct URow { int n; int col[2]; double re[2]; double im[2]; };

constexpr URow urow(int l, int a){
  URow r{};
  const double is2 = 0.70710678118654752440;
  int m = a - l;
  if (m == 0){
    r.n = 1; r.col[0] = l; r.re[0] = 1.0; r.im[0] = 0.0;
  } else if (m > 0){
    r.n = 2;
    r.col[0] = l+m; r.re[0] = (m & 1) ? -is2 : is2; r.im[0] = 0.0;
    r.col[1] = l-m; r.re[1] = is2;                  r.im[1] = 0.0;
  } else {
    int mm = -m; r.n = 2;
    r.col[0] = l-mm; r.re[0] = 0.0; r.im[0] = is2;                   //  i/sqrt2
    r.col[1] = l+mm; r.re[1] = 0.0; r.im[1] = (mm & 1) ? is2 : -is2; // -i*(-1)^m/sqrt2
  }
  return r;
}

struct PTab {
  int nnz;
  unsigned char ia[192];
  unsigned char jb[192];
  unsigned char kc[192];
  float v[192];
};

constexpr PTab build_path(int l1, int l2, int l3){
  double Cc[9][9] = {};
  for (int i = 0; i < 2*l1+1; ++i)
    for (int j = 0; j < 2*l2+1; ++j){
      int m3 = (i-l1)+(j-l2);
      Cc[i][j] = (m3 >= -l3 && m3 <= l3)
               ? cg_complex(l1, i-l1, l2, j-l2, l3, m3) : 0.0;
    }
  PTab t{};
  for (int a = 0; a < 2*l1+1; ++a)
    for (int b = 0; b < 2*l2+1; ++b)
      for (int c = 0; c < 2*l3+1; ++c){
        URow ra = urow(l1,a), rb = urow(l2,b), rc = urow(l3,c);
        double re = 0.0;
        for (int x = 0; x < ra.n; ++x)
          for (int yy = 0; yy < rb.n; ++yy){
            double pr = ra.re[x]*rb.re[yy] - ra.im[x]*rb.im[yy];
            double pi = ra.re[x]*rb.im[yy] + ra.im[x]*rb.re[yy];
            for (int z = 0; z < rc.n; ++z){
              if (rc.col[z]-l3 != (ra.col[x]-l1)+(rb.col[yy]-l2)) continue;
              double ure = pr*rc.re[z] + pi*rc.im[z];
              re += ure * Cc[ra.col[x]][rb.col[yy]];
            }
          }
        if (re > 1e-10 || re < -1e-10){
          t.ia[t.nnz] = (unsigned char)a;
          t.jb[t.nnz] = (unsigned char)b;
          t.kc[t.nnz] = (unsigned char)c;
          t.v[t.nnz]  = (float)re;
          t.nnz++;
        }
      }
  return t;
}

constexpr double PI_D = 3.14159265358979323846264338327950288;
constexpr double Kd(int l, int m){
  double v = csqrt_((2.0*l+1.0)/(4.0*PI_D)*FACT[l-m]/FACT[l+m]);
  if (m) v *= csqrt_(2.0);
  return v;
}

} // namespace cg

// Path list (p, l1, l2, l3) — must match the Python CG_PATHS iteration order.
#define PATHS_X(X) \
  X(0,0,0,0) X(1,0,1,1) X(2,0,2,2) X(3,0,3,3) X(4,0,4,4) \
  X(5,1,0,1) X(6,1,1,0) X(7,1,1,2) X(8,1,2,1) X(9,1,2,3) X(10,1,3,2) X(11,1,3,4) X(12,1,4,3) \
  X(13,2,0,2) X(14,2,1,1) X(15,2,1,3) X(16,2,2,0) X(17,2,2,2) X(18,2,2,4) X(19,2,3,1) X(20,2,3,3) X(21,2,4,2) X(22,2,4,4) \
  X(23,3,0,3) X(24,3,1,2) X(25,3,1,4) X(26,3,2,1) X(27,3,2,3) X(28,3,3,0) X(29,3,3,2) X(30,3,3,4) X(31,3,4,1) X(32,3,4,3) \
  X(33,4,0,4) X(34,4,1,3) X(35,4,2,2) X(36,4,2,4) X(37,4,3,1) X(38,4,3,3) X(39,4,4,0) X(40,4,4,2) X(41,4,4,4)

#define DECL_TAB(P,L1,L2,L3) static constexpr cg::PTab CGT_##P = cg::build_path(L1,L2,L3);
PATHS_X(DECL_TAB)
#undef DECL_TAB

// ==========================================================================
// Group tables: all paths sharing (l1,l2) merged, nnz sorted by (j,i) so the
// product a1[i]*a2[j] is computed once and reused across paths/outputs.
// np[t]: entry starts a new (i,j) product. ft[t]: first write to part[kk].
// ==========================================================================
struct GTab {
  int n;
  int ptot;
  unsigned int zmask;              // part indices never touched (safety)
  unsigned char i8[512], j8[512], kk[512];
  bool np[512], ft[512];
  float v[512];
};

constexpr GTab merge_group(int npaths,
                           const cg::PTab* t0, int l30,
                           const cg::PTab* t1, int l31,
                           const cg::PTab* t2, int l32){
  GTab g{};
  const cg::PTab* ts[3] = {t0, t1, t2};
  int ls[3] = {l30, l31, l32};
  int pofs[3] = {0,0,0};
  int acc = 0;
  for (int s = 0; s < npaths; ++s){ pofs[s] = acc; acc += 2*ls[s]+1; }
  g.ptot = acc;
  bool touched[32] = {};
  for (int j = 0; j < 9; ++j)
    for (int i = 0; i < 9; ++i){
      bool first = true;
      for (int s = 0; s < npaths; ++s){
        const cg::PTab* T = ts[s];
        for (int t = 0; t < T->nnz; ++t){
          if ((int)T->ia[t] == i && (int)T->jb[t] == j){
            int kx = pofs[s] + (int)T->kc[t];
            g.i8[g.n] = (unsigned char)i;
            g.j8[g.n] = (unsigned char)j;
            g.kk[g.n] = (unsigned char)kx;
            g.np[g.n] = first; first = false;
            g.ft[g.n] = !touched[kx]; touched[kx] = true;
            g.v[g.n]  = T->v[t];
            g.n++;
          }
        }
      }
    }
  unsigned int zm = 0;
  for (int k = 0; k < g.ptot; ++k) if (!touched[k]) zm |= (1u << k);
  g.zmask = zm;
  return g;
}

// Groups: X(L1,L2, NP, P0,L30, P1,L31, P2,L32)  (unused slots repeat P0)
#define GROUPS_X(X) \
  X(0,0, 1,  0,0,   0,0,   0,0) \
  X(0,1, 1,  1,1,   1,1,   1,1) \
  X(0,2, 1,  2,2,   2,2,   2,2) \
  X(0,3, 1,  3,3,   3,3,   3,3) \
  X(0,4, 1,  4,4,   4,4,   4,4) \
  X(1,0, 1,  5,1,   5,1,   5,1) \
  X(1,1, 2,  6,0,   7,2,   7,2) \
  X(1,2, 2,  8,1,   9,3,   9,3) \
  X(1,3, 2, 10,2,  11,4,  11,4) \
  X(1,4, 1, 12,3,  12,3,  12,3) \
  X(2,0, 1, 13,2,  13,2,  13,2) \
  X(2,1, 2, 14,1,  15,3,  15,3) \
  X(2,2, 3, 16,0,  17,2,  18,4) \
  X(2,3, 2, 19,1,  20,3,  20,3) \
  X(2,4, 2, 21,2,  22,4,  22,4) \
  X(3,0, 1, 23,3,  23,3,  23,3) \
  X(3,1, 2, 24,2,  25,4,  25,4) \
  X(3,2, 2, 26,1,  27,3,  27,3) \
  X(3,3, 3, 28,0,  29,2,  30,4) \
  X(3,4, 2, 31,1,  32,3,  32,3) \
  X(4,0, 1, 33,4,  33,4,  33,4) \
  X(4,1, 1, 34,3,  34,3,  34,3) \
  X(4,2, 2, 35,2,  36,4,  36,4) \
  X(4,3, 2, 37,1,  38,3,  38,3) \
  X(4,4, 3, 39,0,  40,2,  41,4)

#define DECL_GROUP(L1,L2,NP,P0,L30,P1,L31,P2,L32) \
  static constexpr GTab G_##L1##_##L2 = \
    merge_group(NP, &CGT_##P0, L30, &CGT_##P1, L31, &CGT_##P2, L32);
GROUPS_X(DECL_GROUP)
#undef DECL_GROUP

// Spherical-harmonic normalization constants (incl. sqrt(2) for m>0).
static constexpr float K00=(float)cg::Kd(0,0);
static constexpr float K10=(float)cg::Kd(1,0), K11=(float)cg::Kd(1,1);
static constexpr float K20=(float)cg::Kd(2,0), K21=(float)cg::Kd(2,1), K22=(float)cg::Kd(2,2);
static constexpr float K30=(float)cg::Kd(3,0), K31=(float)cg::Kd(3,1), K32=(float)cg::Kd(3,2), K33=(float)cg::Kd(3,3);
static constexpr float K40=(float)cg::Kd(4,0), K41=(float)cg::Kd(4,1), K42=(float)cg::Kd(4,2), K43=(float)cg::Kd(4,3), K44=(float)cg::Kd(4,4);

static constexpr float PI_F = 3.14159274101257324f; // float32(pi)

// One group-contraction, v2f (two features) wide, fully unrolled & const-folded.
#define RUN_GROUP(GN,L1,L2,NP,P0,L30,P1,L31,P2,L32,S1,S2,DST,WEX) { \
    v2f part[GN.ptot]; \
    _Pragma("unroll") \
    for (int k = 0; k < GN.ptot; ++k) if ((GN.zmask >> k) & 1u) part[k] = vzero; \
    v2f prod = vzero; \
    _Pragma("unroll") \
    for (int t = 0; t < GN.n; ++t) { \
      if (GN.np[t]) prod = S1[(L1)*(L1)+(int)GN.i8[t]] * S2[(L2)*(L2)+(int)GN.j8[t]]; \
      if (GN.ft[t]) part[GN.kk[t]]  = GN.v[t] * prod; \
      else          part[GN.kk[t]] += GN.v[t] * prod; \
    } \
    { const v2f wp = WEX(P0); \
      _Pragma("unroll") for (int k = 0; k < 2*(L30)+1; ++k) \
        DST[(L30)*(L30)+k] += wp * part[k]; } \
    if constexpr ((NP) > 1) { const v2f wp = WEX(P1); \
      _Pragma("unroll") for (int k = 0; k < 2*(L31)+1; ++k) \
        DST[(L31)*(L31)+k] += wp * part[2*(L30)+1 + k]; } \
    if constexpr ((NP) > 2) { const v2f wp = WEX(P2); \
      _Pragma("unroll") for (int k = 0; k < 2*(L32)+1; ++k) \
        DST[(L32)*(L32)+k] += wp * part[2*(L30)+1 + 2*(L31)+1 + k]; } \
  }

#define TP1W(P) (*(const v2f*)(W1p + (P)*16))
#define TP2W(P) (sv * (*(const v2f*)(W2p + (P)*16)))

#define TP1_G(L1,L2,NP,P0,L30,P1,L31,P2,L32) \
  RUN_GROUP(G_##L1##_##L2, L1,L2,NP,P0,L30,P1,L31,P2,L32, a1,a2,y,TP1W)
#define TP2_G(L1,L2,NP,P0,L30,P1,L31,P2,L32) \
  RUN_GROUP(G_##L1##_##L2, L1,L2,NP,P0,L30,P1,L31,P2,L32, y,Ys,o,TP2W)

// One thread per (edge, feature-pair): f2 = 2*(g&7) covers features f2,f2+1
// as a v2f -> every TP op becomes v_pk_*_f32 (packed fp32, 2 FLOP-pairs/inst).
// waves_per_eu(2,2): 256-VGPR budget (live set ~200), scheduler targets 2
// waves/EU — VALU-bound kernel with massive ILP tolerates low occupancy.
__global__ __launch_bounds__(256)
__attribute__((amdgpu_waves_per_eu(2, 2)))
void bctmd_kernel(
    const float* __restrict__ A,    // (N,1,25,16)
    const float* __restrict__ D,    // (E,3)
    const float* __restrict__ W1,   // (42,16)
    const float* __restrict__ W2,   // (42,16)
    const int*   __restrict__ NI,   // (E,)
    const int*   __restrict__ NJ,   // (E,)
    float* __restrict__ out,        // (E,1,25,16)
    int E)
{
  const v2f vzero = {0.f, 0.f};
  int g  = blockIdx.x * 256 + threadIdx.x;
  int e  = g >> 3;
  int f2 = (g & 7) * 2;
  if (e >= E) return;

  const float* __restrict__ a1p = A + (size_t)NI[e] * 400 + f2;
  const float* __restrict__ a2p = A + (size_t)NJ[e] * 400 + f2;
  const float* __restrict__ W1p = W1 + f2;
  const float* __restrict__ W2p = W2 + f2;

  v2f a1[25], a2[25];
#pragma unroll
  for (int i = 0; i < 25; ++i) a1[i] = *(const v2f*)(a1p + i*16);
#pragma unroll
  for (int i = 0; i < 25; ++i) a2[i] = *(const v2f*)(a2p + i*16);

  // ---- TP1: y[k] = sum_p w1[p] * sum_{ij} cg_p[i,j,k] a1[i] a2[j]
  v2f y[25];
#pragma unroll
  for (int i = 0; i < 25; ++i) y[i] = vzero;
  GROUPS_X(TP1_G)

  // ---- bond basis: Y_sph(25) scalar (shared by both features)
  float dx = D[3*e], dy = D[3*e+1], dz = D[3*e+2];
  float r2 = dx*dx + dy*dy + dz*dz + 1e-12f;
  float inv = __builtin_amdgcn_rsqf(r2);
  float r   = r2 * inv;
  float ux = dx*inv, uy = dy*inv, uz = dz*inv;

  float Ys[25];
  {
    float C1 = ux,            S1 = uy;
    float C2 = ux*C1 - uy*S1, S2 = ux*S1 + uy*C1;
    float C3 = ux*C2 - uy*S2, S3 = ux*S2 + uy*C2;
    float C4 = ux*C3 - uy*S3, S4 = ux*S3 + uy*C3;
    float z = uz;
    float Q00 = 1.f;
    float Q11 = 1.f, Q22 = 3.f, Q33 = 15.f, Q44 = 105.f;
    float Q10 = z, Q21 = 3.f*z, Q32 = 15.f*z, Q43 = 105.f*z;
    float Q20 = 0.5f*(3.f*z*Q10 - Q00);
    float Q31 = 0.5f*(5.f*z*Q21 - 3.f*Q11);
    float Q42 = 0.5f*(7.f*z*Q32 - 5.f*Q22);
    float Q30 = (5.f*z*Q20 - 2.f*Q10)*(1.f/3.f);
    float Q41 = (7.f*z*Q31 - 4.f*Q21)*(1.f/3.f);
    float Q40 = 0.25f*(7.f*z*Q30 - 3.f*Q20);

    Ys[0]  = K00*Q00;
    Ys[1]  = K11*Q11*S1;  Ys[2]  = K10*Q10;     Ys[3]  = K11*Q11*C1;
    Ys[4]  = K22*Q22*S2;  Ys[5]  = K21*Q21*S1;  Ys[6]  = K20*Q20;
    Ys[7]  = K21*Q21*C1;  Ys[8]  = K22*Q22*C2;
    Ys[9]  = K33*Q33*S3;  Ys[10] = K32*Q32*S2;  Ys[11] = K31*Q31*S1;
    Ys[12] = K30*Q30;     Ys[13] = K31*Q31*C1;  Ys[14] = K32*Q32*C2;
    Ys[15] = K33*Q33*C3;
    Ys[16] = K44*Q44*S4;  Ys[17] = K43*Q43*S3;  Ys[18] = K42*Q42*S2;
    Ys[19] = K41*Q41*S1;  Ys[20] = K40*Q40;     Ys[21] = K41*Q41*C1;
    Ys[22] = K42*Q42*C2;  Ys[23] = K43*Q43*C3;  Ys[24] = K44*Q44*C4;
  }

  // radial sinc per feature (k = f+1), cosine cutoff (shared).
  float base = PI_F * r * 0.2f;
  float tt0  = base * (float)(f2+1);
  float tt1  = base * (float)(f2+2);
  float rad0 = __sinf(tt0) * __builtin_amdgcn_rcpf(tt0);
  float rad1 = __sinf(tt1) * __builtin_amdgcn_rcpf(tt1);
  float cut  = (r < 5.0f) ? 0.5f*(1.0f + __cosf(base)) : 0.0f;
  v2f sv; sv.x = rad0*cut; sv.y = rad1*cut;

  // ---- TP2: out[k] = sum_p (w2[p]*rad*cut) * sum_{ij} cg_p[i,j,k] y[i] Ys[j]
  v2f o[25];
#pragma unroll
  for (int i = 0; i < 25; ++i) o[i] = vzero;
  GROUPS_X(TP2_G)

  float* __restrict__ op = out + (size_t)e * 400 + f2;
#pragma unroll
  for (int k = 0; k < 25; ++k) *(v2f*)(op + k*16) = o[k];
}

extern "C" void kernel_launch(void* const* d_in, const int* in_sizes, int n_in,
                              void* d_out, int out_size, void* d_ws, size_t ws_size,
                              hipStream_t stream) {
  const float* A  = (const float*)d_in[0];
  const float* D  = (const float*)d_in[1];
  const float* W1 = (const float*)d_in[2];
  const float* W2 = (const float*)d_in[3];
  const int*   NI = (const int*)d_in[4];
  const int*   NJ = (const int*)d_in[5];
  float* out = (float*)d_out;

  int E = in_sizes[4];
  long total = (long)E * 8;               // one thread per (edge, feature-pair)
  int block = 256;
  int grid = (int)((total + block - 1) / block);
  bctmd_kernel<<<grid, block, 0, stream>>>(A, D, W1, W2, NI, NJ, out, E);
}

// Round 4
// 281.900 us; speedup vs baseline: 1.0129x; 1.0129x over previous
//
#include <hip/hip_runtime.h>

typedef float v2f __attribute__((ext_vector_type(2)));

// ==========================================================================
// Compile-time Clebsch-Gordan (real basis) table generation.
// Mirrors the reference Python exactly: _cg_complex, _u_matrix, _real_cg.
// ==========================================================================
namespace cg {

constexpr double FACT[16] = {
  1.0, 1.0, 2.0, 6.0, 24.0, 120.0, 720.0, 5040.0, 40320.0, 362880.0,
  3628800.0, 39916800.0, 479001600.0, 6227020800.0, 87178291200.0,
  1307674368000.0 };

constexpr double csqrt_(double x){
  if (x <= 0.0) return 0.0;
  double xx = x, g = 1.0;
  while (xx >= 256.0)      { xx *= (1.0/256.0); g *= 16.0;       }
  while (xx >= 4.0)        { xx *= 0.25;        g *= 2.0;        }
  while (xx < (1.0/256.0)) { xx *= 256.0;       g *= (1.0/16.0); }
  while (xx < 1.0)         { xx *= 4.0;         g *= 0.5;        }
  double s = 1.5;
  for (int i = 0; i < 10; ++i) s = 0.5*(s + xx/s);
  return g*s;
}

constexpr double cg_complex(int j1,int m1,int j2,int m2,int j3,int m3){
  if (m1+m2 != m3) return 0.0;
  int dj = j1-j2; if (dj < 0) dj = -dj;
  if (j3 < dj || j3 > j1+j2) return 0.0;
  if (m1<-j1||m1>j1||m2<-j2||m2>j2||m3<-j3||m3>j3) return 0.0;
  double pre = csqrt_((2.0*j3+1.0)*FACT[j1+j2-j3]*FACT[j1-j2+j3]*FACT[-j1+j2+j3]/FACT[j1+j2+j3+1]);
  pre *= csqrt_(FACT[j1+m1]*FACT[j1-m1]*FACT[j2+m2]*FACT[j2-m2]*FACT[j3+m3]*FACT[j3-m3]);
  double s = 0.0;
  for (int k = 0; k <= j1+j2+j3; ++k){
    int t1=j1+j2-j3-k, t2=j1-m1-k, t3=j2+m2-k, t4=j3-j2+m1+k, t5=j3-j1-m2+k;
    if (t1<0||t2<0||t3<0||t4<0||t5<0) continue;
    double term = 1.0/(FACT[k]*FACT[t1]*FACT[t2]*FACT[t3]*FACT[t4]*FACT[t5]);
    s += (k & 1) ? -term : term;
  }
  return pre*s;
}

struct URow { int n; int col[2]; double re[2]; double im[2]; };

constexpr URow urow(int l, int a){
  URow r{};
  const double is2 = 0.70710678118654752440;
  int m = a - l;
  if (m == 0){
    r.n = 1; r.col[0] = l; r.re[0] = 1.0; r.im[0] = 0.0;
  } else if (m > 0){
    r.n = 2;
    r.col[0] = l+m; r.re[0] = (m & 1) ? -is2 : is2; r.im[0] = 0.0;
    r.col[1] = l-m; r.re[1] = is2;                  r.im[1] = 0.0;
  } else {
    int mm = -m; r.n = 2;
    r.col[0] = l-mm; r.re[0] = 0.0; r.im[0] = is2;                   //  i/sqrt2
    r.col[1] = l+mm; r.re[1] = 0.0; r.im[1] = (mm & 1) ? is2 : -is2; // -i*(-1)^m/sqrt2
  }
  return r;
}

struct PTab {
  int nnz;
  unsigned char ia[192];
  unsigned char jb[192];
  unsigned char kc[192];
  float v[192];
};

constexpr PTab build_path(int l1, int l2, int l3){
  double Cc[9][9] = {};
  for (int i = 0; i < 2*l1+1; ++i)
    for (int j = 0; j < 2*l2+1; ++j){
      int m3 = (i-l1)+(j-l2);
      Cc[i][j] = (m3 >= -l3 && m3 <= l3)
               ? cg_complex(l1, i-l1, l2, j-l2, l3, m3) : 0.0;
    }
  PTab t{};
  for (int a = 0; a < 2*l1+1; ++a)
    for (int b = 0; b < 2*l2+1; ++b)
      for (int c = 0; c < 2*l3+1; ++c){
        URow ra = urow(l1,a), rb = urow(l2,b), rc = urow(l3,c);
        double re = 0.0;
        for (int x = 0; x < ra.n; ++x)
          for (int yy = 0; yy < rb.n; ++yy){
            double pr = ra.re[x]*rb.re[yy] - ra.im[x]*rb.im[yy];
            double pi = ra.re[x]*rb.im[yy] + ra.im[x]*rb.re[yy];
            for (int z = 0; z < rc.n; ++z){
              if (rc.col[z]-l3 != (ra.col[x]-l1)+(rb.col[yy]-l2)) continue;
              double ure = pr*rc.re[z] + pi*rc.im[z];
              re += ure * Cc[ra.col[x]][rb.col[yy]];
            }
          }
        if (re > 1e-10 || re < -1e-10){
          t.ia[t.nnz] = (unsigned char)a;
          t.jb[t.nnz] = (unsigned char)b;
          t.kc[t.nnz] = (unsigned char)c;
          t.v[t.nnz]  = (float)re;
          t.nnz++;
        }
      }
  return t;
}

constexpr double PI_D = 3.14159265358979323846264338327950288;
constexpr double Kd(int l, int m){
  double v = csqrt_((2.0*l+1.0)/(4.0*PI_D)*FACT[l-m]/FACT[l+m]);
  if (m) v *= csqrt_(2.0);
  return v;
}

} // namespace cg

// Path list (p, l1, l2, l3) — must match the Python CG_PATHS iteration order.
#define PATHS_X(X) \
  X(0,0,0,0) X(1,0,1,1) X(2,0,2,2) X(3,0,3,3) X(4,0,4,4) \
  X(5,1,0,1) X(6,1,1,0) X(7,1,1,2) X(8,1,2,1) X(9,1,2,3) X(10,1,3,2) X(11,1,3,4) X(12,1,4,3) \
  X(13,2,0,2) X(14,2,1,1) X(15,2,1,3) X(16,2,2,0) X(17,2,2,2) X(18,2,2,4) X(19,2,3,1) X(20,2,3,3) X(21,2,4,2) X(22,2,4,4) \
  X(23,3,0,3) X(24,3,1,2) X(25,3,1,4) X(26,3,2,1) X(27,3,2,3) X(28,3,3,0) X(29,3,3,2) X(30,3,3,4) X(31,3,4,1) X(32,3,4,3) \
  X(33,4,0,4) X(34,4,1,3) X(35,4,2,2) X(36,4,2,4) X(37,4,3,1) X(38,4,3,3) X(39,4,4,0) X(40,4,4,2) X(41,4,4,4)

#define DECL_TAB(P,L1,L2,L3) static constexpr cg::PTab CGT_##P = cg::build_path(L1,L2,L3);
PATHS_X(DECL_TAB)
#undef DECL_TAB

// ==========================================================================
// Group tables: all paths sharing (l1,l2) merged, nnz sorted by (j,i) so the
// product a1[i]*a2[j] is computed once and reused across paths/outputs.
// ==========================================================================
struct GTab {
  int n;
  int ptot;
  unsigned int zmask;              // part indices never touched (safety)
  unsigned char i8[512], j8[512], kk[512];
  bool np[512], ft[512];
  float v[512];
};

constexpr GTab merge_group(int npaths,
                           const cg::PTab* t0, int l30,
                           const cg::PTab* t1, int l31,
                           const cg::PTab* t2, int l32){
  GTab g{};
  const cg::PTab* ts[3] = {t0, t1, t2};
  int ls[3] = {l30, l31, l32};
  int pofs[3] = {0,0,0};
  int acc = 0;
  for (int s = 0; s < npaths; ++s){ pofs[s] = acc; acc += 2*ls[s]+1; }
  g.ptot = acc;
  bool touched[32] = {};
  for (int j = 0; j < 9; ++j)
    for (int i = 0; i < 9; ++i){
      bool first = true;
      for (int s = 0; s < npaths; ++s){
        const cg::PTab* T = ts[s];
        for (int t = 0; t < T->nnz; ++t){
          if ((int)T->ia[t] == i && (int)T->jb[t] == j){
            int kx = pofs[s] + (int)T->kc[t];
            g.i8[g.n] = (unsigned char)i;
            g.j8[g.n] = (unsigned char)j;
            g.kk[g.n] = (unsigned char)kx;
            g.np[g.n] = first; first = false;
            g.ft[g.n] = !touched[kx]; touched[kx] = true;
            g.v[g.n]  = T->v[t];
            g.n++;
          }
        }
      }
    }
  unsigned int zm = 0;
  for (int k = 0; k < g.ptot; ++k) if (!touched[k]) zm |= (1u << k);
  g.zmask = zm;
  return g;
}

// Groups: X(L1,L2, NP, P0,L30, P1,L31, P2,L32)  (unused slots repeat P0)
#define GROUPS_X(X) \
  X(0,0, 1,  0,0,   0,0,   0,0) \
  X(0,1, 1,  1,1,   1,1,   1,1) \
  X(0,2, 1,  2,2,   2,2,   2,2) \
  X(0,3, 1,  3,3,   3,3,   3,3) \
  X(0,4, 1,  4,4,   4,4,   4,4) \
  X(1,0, 1,  5,1,   5,1,   5,1) \
  X(1,1, 2,  6,0,   7,2,   7,2) \
  X(1,2, 2,  8,1,   9,3,   9,3) \
  X(1,3, 2, 10,2,  11,4,  11,4) \
  X(1,4, 1, 12,3,  12,3,  12,3) \
  X(2,0, 1, 13,2,  13,2,  13,2) \
  X(2,1, 2, 14,1,  15,3,  15,3) \
  X(2,2, 3, 16,0,  17,2,  18,4) \
  X(2,3, 2, 19,1,  20,3,  20,3) \
  X(2,4, 2, 21,2,  22,4,  22,4) \
  X(3,0, 1, 23,3,  23,3,  23,3) \
  X(3,1, 2, 24,2,  25,4,  25,4) \
  X(3,2, 2, 26,1,  27,3,  27,3) \
  X(3,3, 3, 28,0,  29,2,  30,4) \
  X(3,4, 2, 31,1,  32,3,  32,3) \
  X(4,0, 1, 33,4,  33,4,  33,4) \
  X(4,1, 1, 34,3,  34,3,  34,3) \
  X(4,2, 2, 35,2,  36,4,  36,4) \
  X(4,3, 2, 37,1,  38,3,  38,3) \
  X(4,4, 3, 39,0,  40,2,  41,4)

#define DECL_GROUP(L1,L2,NP,P0,L30,P1,L31,P2,L32) \
  static constexpr GTab G_##L1##_##L2 = \
    merge_group(NP, &CGT_##P0, L30, &CGT_##P1, L31, &CGT_##P2, L32);
GROUPS_X(DECL_GROUP)
#undef DECL_GROUP

// Spherical-harmonic normalization constants (incl. sqrt(2) for m>0).
static constexpr float K00=(float)cg::Kd(0,0);
static constexpr float K10=(float)cg::Kd(1,0), K11=(float)cg::Kd(1,1);
static constexpr float K20=(float)cg::Kd(2,0), K21=(float)cg::Kd(2,1), K22=(float)cg::Kd(2,2);
static constexpr float K30=(float)cg::Kd(3,0), K31=(float)cg::Kd(3,1), K32=(float)cg::Kd(3,2), K33=(float)cg::Kd(3,3);
static constexpr float K40=(float)cg::Kd(4,0), K41=(float)cg::Kd(4,1), K42=(float)cg::Kd(4,2), K43=(float)cg::Kd(4,3), K44=(float)cg::Kd(4,4);

static constexpr float PI_F = 3.14159274101257324f; // float32(pi)

// One group-contraction, v2f (two features) wide, fully unrolled & const-folded.
#define RUN_GROUP(GN,L1,L2,NP,P0,L30,P1,L31,P2,L32,S1,S2,DST,WEX) { \
    v2f part[GN.ptot]; \
    _Pragma("unroll") \
    for (int k = 0; k < GN.ptot; ++k) if ((GN.zmask >> k) & 1u) part[k] = vzero; \
    v2f prod = vzero; \
    _Pragma("unroll") \
    for (int t = 0; t < GN.n; ++t) { \
      if (GN.np[t]) prod = S1[(L1)*(L1)+(int)GN.i8[t]] * S2[(L2)*(L2)+(int)GN.j8[t]]; \
      if (GN.ft[t]) part[GN.kk[t]]  = GN.v[t] * prod; \
      else          part[GN.kk[t]] += GN.v[t] * prod; \
    } \
    { const v2f wp = WEX(P0); \
      _Pragma("unroll") for (int k = 0; k < 2*(L30)+1; ++k) \
        DST[(L30)*(L30)+k] += wp * part[k]; } \
    if constexpr ((NP) > 1) { const v2f wp = WEX(P1); \
      _Pragma("unroll") for (int k = 0; k < 2*(L31)+1; ++k) \
        DST[(L31)*(L31)+k] += wp * part[2*(L30)+1 + k]; } \
    if constexpr ((NP) > 2) { const v2f wp = WEX(P2); \
      _Pragma("unroll") for (int k = 0; k < 2*(L32)+1; ++k) \
        DST[(L32)*(L32)+k] += wp * part[2*(L30)+1 + 2*(L31)+1 + k]; } \
  }

#define TP1W(P) (*(const v2f*)(W1p + (P)*16))
#define TP2W(P) (sv * (*(const v2f*)(W2p + (P)*16)))

#define TP1_G(L1,L2,NP,P0,L30,P1,L31,P2,L32) \
  RUN_GROUP(G_##L1##_##L2, L1,L2,NP,P0,L30,P1,L31,P2,L32, a1,a2,y,TP1W)
#define TP2_G(L1,L2,NP,P0,L30,P1,L31,P2,L32) \
  RUN_GROUP(G_##L1##_##L2, L1,L2,NP,P0,L30,P1,L31,P2,L32, y,Ys,o,TP2W)

// One thread per (edge, feature-pair): f2 = 2*(g&7) covers features f2,f2+1
// as a v2f -> TP ops lower to v_pk_*_f32 (packed fp32, 2 lanes-worth/inst).
// NO occupancy attributes: round-3 showed forcing 2 waves/EU removes the
// latency hiding the compiler's reload-style regalloc depends on. Let the
// default heuristic pick occupancy; VALU inst count is halved vs scalar.
__global__ __launch_bounds__(256)
void bctmd_kernel(
    const float* __restrict__ A,    // (N,1,25,16)
    const float* __restrict__ D,    // (E,3)
    const float* __restrict__ W1,   // (42,16)
    const float* __restrict__ W2,   // (42,16)
    const int*   __restrict__ NI,   // (E,)
    const int*   __restrict__ NJ,   // (E,)
    float* __restrict__ out,        // (E,1,25,16)
    int E)
{
  const v2f vzero = {0.f, 0.f};
  int g  = blockIdx.x * 256 + threadIdx.x;
  int e  = g >> 3;
  int f2 = (g & 7) * 2;
  if (e >= E) return;

  const float* __restrict__ a1p = A + (size_t)NI[e] * 400 + f2;
  const float* __restrict__ a2p = A + (size_t)NJ[e] * 400 + f2;
  const float* __restrict__ W1p = W1 + f2;
  const float* __restrict__ W2p = W2 + f2;

  v2f a1[25], a2[25];
#pragma unroll
  for (int i = 0; i < 25; ++i) a1[i] = *(const v2f*)(a1p + i*16);
#pragma unroll
  for (int i = 0; i < 25; ++i) a2[i] = *(const v2f*)(a2p + i*16);

  // ---- TP1: y[k] = sum_p w1[p] * sum_{ij} cg_p[i,j,k] a1[i] a2[j]
  v2f y[25];
#pragma unroll
  for (int i = 0; i < 25; ++i) y[i] = vzero;
  GROUPS_X(TP1_G)

  // ---- bond basis: Y_sph(25) scalar (shared by both features)
  float dx = D[3*e], dy = D[3*e+1], dz = D[3*e+2];
  float r2 = dx*dx + dy*dy + dz*dz + 1e-12f;
  float inv = __builtin_amdgcn_rsqf(r2);
  float r   = r2 * inv;
  float ux = dx*inv, uy = dy*inv, uz = dz*inv;

  float Ys[25];
  {
    float C1 = ux,            S1 = uy;
    float C2 = ux*C1 - uy*S1, S2 = ux*S1 + uy*C1;
    float C3 = ux*C2 - uy*S2, S3 = ux*S2 + uy*C2;
    float C4 = ux*C3 - uy*S3, S4 = ux*S3 + uy*C3;
    float z = uz;
    float Q00 = 1.f;
    float Q11 = 1.f, Q22 = 3.f, Q33 = 15.f, Q44 = 105.f;
    float Q10 = z, Q21 = 3.f*z, Q32 = 15.f*z, Q43 = 105.f*z;
    float Q20 = 0.5f*(3.f*z*Q10 - Q00);
    float Q31 = 0.5f*(5.f*z*Q21 - 3.f*Q11);
    float Q42 = 0.5f*(7.f*z*Q32 - 5.f*Q22);
    float Q30 = (5.f*z*Q20 - 2.f*Q10)*(1.f/3.f);
    float Q41 = (7.f*z*Q31 - 4.f*Q21)*(1.f/3.f);
    float Q40 = 0.25f*(7.f*z*Q30 - 3.f*Q20);

    Ys[0]  = K00*Q00;
    Ys[1]  = K11*Q11*S1;  Ys[2]  = K10*Q10;     Ys[3]  = K11*Q11*C1;
    Ys[4]  = K22*Q22*S2;  Ys[5]  = K21*Q21*S1;  Ys[6]  = K20*Q20;
    Ys[7]  = K21*Q21*C1;  Ys[8]  = K22*Q22*C2;
    Ys[9]  = K33*Q33*S3;  Ys[10] = K32*Q32*S2;  Ys[11] = K31*Q31*S1;
    Ys[12] = K30*Q30;     Ys[13] = K31*Q31*C1;  Ys[14] = K32*Q32*C2;
    Ys[15] = K33*Q33*C3;
    Ys[16] = K44*Q44*S4;  Ys[17] = K43*Q43*S3;  Ys[18] = K42*Q42*S2;
    Ys[19] = K41*Q41*S1;  Ys[20] = K40*Q40;     Ys[21] = K41*Q41*C1;
    Ys[22] = K42*Q42*C2;  Ys[23] = K43*Q43*C3;  Ys[24] = K44*Q44*C4;
  }

  // radial sinc per feature (k = f+1), cosine cutoff (shared).
  float base = PI_F * r * 0.2f;
  float tt0  = base * (float)(f2+1);
  float tt1  = base * (float)(f2+2);
  float rad0 = __sinf(tt0) * __builtin_amdgcn_rcpf(tt0);
  float rad1 = __sinf(tt1) * __builtin_amdgcn_rcpf(tt1);
  float cut  = (r < 5.0f) ? 0.5f*(1.0f + __cosf(base)) : 0.0f;
  v2f sv; sv.x = rad0*cut; sv.y = rad1*cut;

  // ---- TP2: out[k] = sum_p (w2[p]*rad*cut) * sum_{ij} cg_p[i,j,k] y[i] Ys[j]
  v2f o[25];
#pragma unroll
  for (int i = 0; i < 25; ++i) o[i] = vzero;
  GROUPS_X(TP2_G)

  float* __restrict__ op = out + (size_t)e * 400 + f2;
#pragma unroll
  for (int k = 0; k < 25; ++k) *(v2f*)(op + k*16) = o[k];
}

extern "C" void kernel_launch(void* const* d_in, const int* in_sizes, int n_in,
                              void* d_out, int out_size, void* d_ws, size_t ws_size,
                              hipStream_t stream) {
  const float* A  = (const float*)d_in[0];
  const float* D  = (const float*)d_in[1];
  const float* W1 = (const float*)d_in[2];
  const float* W2 = (const float*)d_in[3];
  const int*   NI = (const int*)d_in[4];
  const int*   NJ = (const int*)d_in[5];
  float* out = (float*)d_out;

  int E = in_sizes[4];
  long total = (long)E * 8;               // one thread per (edge, feature-pair)
  int block = 256;
  int grid = (int)((total + block - 1) / block);
  bctmd_kernel<<<grid, block, 0, stream>>>(A, D, W1, W2, NI, NJ, out, E);
}

// Round 5
// 215.164 us; speedup vs baseline: 1.3271x; 1.3102x over previous
//
#include <hip/hip_runtime.h>

// ==========================================================================
// Compile-time Clebsch-Gordan (real basis) table generation.
// Mirrors the reference Python exactly: _cg_complex, _u_matrix, _real_cg.
// ==========================================================================
namespace cg {

constexpr double FACT[16] = {
  1.0, 1.0, 2.0, 6.0, 24.0, 120.0, 720.0, 5040.0, 40320.0, 362880.0,
  3628800.0, 39916800.0, 479001600.0, 6227020800.0, 87178291200.0,
  1307674368000.0 };

constexpr double csqrt_(double x){
  if (x <= 0.0) return 0.0;
  double xx = x, g = 1.0;
  while (xx >= 256.0)      { xx *= (1.0/256.0); g *= 16.0;       }
  while (xx >= 4.0)        { xx *= 0.25;        g *= 2.0;        }
  while (xx < (1.0/256.0)) { xx *= 256.0;       g *= (1.0/16.0); }
  while (xx < 1.0)         { xx *= 4.0;         g *= 0.5;        }
  double s = 1.5;
  for (int i = 0; i < 10; ++i) s = 0.5*(s + xx/s);
  return g*s;
}

constexpr double cg_complex(int j1,int m1,int j2,int m2,int j3,int m3){
  if (m1+m2 != m3) return 0.0;
  int dj = j1-j2; if (dj < 0) dj = -dj;
  if (j3 < dj || j3 > j1+j2) return 0.0;
  if (m1<-j1||m1>j1||m2<-j2||m2>j2||m3<-j3||m3>j3) return 0.0;
  double pre = csqrt_((2.0*j3+1.0)*FACT[j1+j2-j3]*FACT[j1-j2+j3]*FACT[-j1+j2+j3]/FACT[j1+j2+j3+1]);
  pre *= csqrt_(FACT[j1+m1]*FACT[j1-m1]*FACT[j2+m2]*FACT[j2-m2]*FACT[j3+m3]*FACT[j3-m3]);
  double s = 0.0;
  for (int k = 0; k <= j1+j2+j3; ++k){
    int t1=j1+j2-j3-k, t2=j1-m1-k, t3=j2+m2-k, t4=j3-j2+m1+k, t5=j3-j1-m2+k;
    if (t1<0||t2<0||t3<0||t4<0||t5<0) continue;
    double term = 1.0/(FACT[k]*FACT[t1]*FACT[t2]*FACT[t3]*FACT[t4]*FACT[t5]);
    s += (k & 1) ? -term : term;
  }
  return pre*s;
}

struct URow { int n; int col[2]; double re[2]; double im[2]; };

constexpr URow urow(int l, int a){
  URow r{};
  const double is2 = 0.70710678118654752440;
  int m = a - l;
  if (m == 0){
    r.n = 1; r.col[0] = l; r.re[0] = 1.0; r.im[0] = 0.0;
  } else if (m > 0){
    r.n = 2;
    r.col[0] = l+m; r.re[0] = (m & 1) ? -is2 : is2; r.im[0] = 0.0;
    r.col[1] = l-m; r.re[1] = is2;                  r.im[1] = 0.0;
  } else {
    int mm = -m; r.n = 2;
    r.col[0] = l-mm; r.re[0] = 0.0; r.im[0] = is2;                   //  i/sqrt2
    r.col[1] = l+mm; r.re[1] = 0.0; r.im[1] = (mm & 1) ? is2 : -is2; // -i*(-1)^m/sqrt2
  }
  return r;
}

struct PTab {
  int nnz;
  unsigned char ia[192];
  unsigned char jb[192];
  unsigned char kc[192];
  float v[192];
};

constexpr PTab build_path(int l1, int l2, int l3){
  double Cc[9][9] = {};
  for (int i = 0; i < 2*l1+1; ++i)
    for (int j = 0; j < 2*l2+1; ++j){
      int m3 = (i-l1)+(j-l2);
      Cc[i][j] = (m3 >= -l3 && m3 <= l3)
               ? cg_complex(l1, i-l1, l2, j-l2, l3, m3) : 0.0;
    }
  PTab t{};
  for (int a = 0; a < 2*l1+1; ++a)
    for (int b = 0; b < 2*l2+1; ++b)
      for (int c = 0; c < 2*l3+1; ++c){
        URow ra = urow(l1,a), rb = urow(l2,b), rc = urow(l3,c);
        double re = 0.0;
        for (int x = 0; x < ra.n; ++x)
          for (int yy = 0; yy < rb.n; ++yy){
            double pr = ra.re[x]*rb.re[yy] - ra.im[x]*rb.im[yy];
            double pi = ra.re[x]*rb.im[yy] + ra.im[x]*rb.re[yy];
            for (int z = 0; z < rc.n; ++z){
              if (rc.col[z]-l3 != (ra.col[x]-l1)+(rb.col[yy]-l2)) continue;
              double ure = pr*rc.re[z] + pi*rc.im[z];
              re += ure * Cc[ra.col[x]][rb.col[yy]];
            }
          }
        if (re > 1e-10 || re < -1e-10){
          t.ia[t.nnz] = (unsigned char)a;
          t.jb[t.nnz] = (unsigned char)b;
          t.kc[t.nnz] = (unsigned char)c;
          t.v[t.nnz]  = (float)re;
          t.nnz++;
        }
      }
  return t;
}

constexpr double PI_D = 3.14159265358979323846264338327950288;
constexpr double Kd(int l, int m){
  double v = csqrt_((2.0*l+1.0)/(4.0*PI_D)*FACT[l-m]/FACT[l+m]);
  if (m) v *= csqrt_(2.0);
  return v;
}

} // namespace cg

// Path list (p, l1, l2, l3) — must match the Python CG_PATHS iteration order.
#define PATHS_X(X) \
  X(0,0,0,0) X(1,0,1,1) X(2,0,2,2) X(3,0,3,3) X(4,0,4,4) \
  X(5,1,0,1) X(6,1,1,0) X(7,1,1,2) X(8,1,2,1) X(9,1,2,3) X(10,1,3,2) X(11,1,3,4) X(12,1,4,3) \
  X(13,2,0,2) X(14,2,1,1) X(15,2,1,3) X(16,2,2,0) X(17,2,2,2) X(18,2,2,4) X(19,2,3,1) X(20,2,3,3) X(21,2,4,2) X(22,2,4,4) \
  X(23,3,0,3) X(24,3,1,2) X(25,3,1,4) X(26,3,2,1) X(27,3,2,3) X(28,3,3,0) X(29,3,3,2) X(30,3,3,4) X(31,3,4,1) X(32,3,4,3) \
  X(33,4,0,4) X(34,4,1,3) X(35,4,2,2) X(36,4,2,4) X(37,4,3,1) X(38,4,3,3) X(39,4,4,0) X(40,4,4,2) X(41,4,4,4)

#define DECL_TAB(P,L1,L2,L3) static constexpr cg::PTab CGT_##P = cg::build_path(L1,L2,L3);
PATHS_X(DECL_TAB)
#undef DECL_TAB

// ==========================================================================
// Group tables: all paths sharing (l1,l2) merged, nnz sorted by (j,i) so the
// product a1[i]*a2[j] is computed once and reused across paths/outputs.
// np[t]: entry starts a new (i,j) product. ft[t]: first write to part[kk].
// ==========================================================================
struct GTab {
  int n;
  int ptot;
  unsigned int zmask;              // part indices never touched (safety)
  unsigned char i8[512], j8[512], kk[512];
  bool np[512], ft[512];
  float v[512];
};

constexpr GTab merge_group(int npaths,
                           const cg::PTab* t0, int l30,
                           const cg::PTab* t1, int l31,
                           const cg::PTab* t2, int l32){
  GTab g{};
  const cg::PTab* ts[3] = {t0, t1, t2};
  int ls[3] = {l30, l31, l32};
  int pofs[3] = {0,0,0};
  int acc = 0;
  for (int s = 0; s < npaths; ++s){ pofs[s] = acc; acc += 2*ls[s]+1; }
  g.ptot = acc;
  bool touched[32] = {};
  for (int j = 0; j < 9; ++j)
    for (int i = 0; i < 9; ++i){
      bool first = true;
      for (int s = 0; s < npaths; ++s){
        const cg::PTab* T = ts[s];
        for (int t = 0; t < T->nnz; ++t){
          if ((int)T->ia[t] == i && (int)T->jb[t] == j){
            int kx = pofs[s] + (int)T->kc[t];
            g.i8[g.n] = (unsigned char)i;
            g.j8[g.n] = (unsigned char)j;
            g.kk[g.n] = (unsigned char)kx;
            g.np[g.n] = first; first = false;
            g.ft[g.n] = !touched[kx]; touched[kx] = true;
            g.v[g.n]  = T->v[t];
            g.n++;
          }
        }
      }
    }
  unsigned int zm = 0;
  for (int k = 0; k < g.ptot; ++k) if (!touched[k]) zm |= (1u << k);
  g.zmask = zm;
  return g;
}

// Groups: X(L1,L2, NP, P0,L30, P1,L31, P2,L32)  (unused slots repeat P0)
#define GROUPS_X(X) \
  X(0,0, 1,  0,0,   0,0,   0,0) \
  X(0,1, 1,  1,1,   1,1,   1,1) \
  X(0,2, 1,  2,2,   2,2,   2,2) \
  X(0,3, 1,  3,3,   3,3,   3,3) \
  X(0,4, 1,  4,4,   4,4,   4,4) \
  X(1,0, 1,  5,1,   5,1,   5,1) \
  X(1,1, 2,  6,0,   7,2,   7,2) \
  X(1,2, 2,  8,1,   9,3,   9,3) \
  X(1,3, 2, 10,2,  11,4,  11,4) \
  X(1,4, 1, 12,3,  12,3,  12,3) \
  X(2,0, 1, 13,2,  13,2,  13,2) \
  X(2,1, 2, 14,1,  15,3,  15,3) \
  X(2,2, 3, 16,0,  17,2,  18,4) \
  X(2,3, 2, 19,1,  20,3,  20,3) \
  X(2,4, 2, 21,2,  22,4,  22,4) \
  X(3,0, 1, 23,3,  23,3,  23,3) \
  X(3,1, 2, 24,2,  25,4,  25,4) \
  X(3,2, 2, 26,1,  27,3,  27,3) \
  X(3,3, 3, 28,0,  29,2,  30,4) \
  X(3,4, 2, 31,1,  32,3,  32,3) \
  X(4,0, 1, 33,4,  33,4,  33,4) \
  X(4,1, 1, 34,3,  34,3,  34,3) \
  X(4,2, 2, 35,2,  36,4,  36,4) \
  X(4,3, 2, 37,1,  38,3,  38,3) \
  X(4,4, 3, 39,0,  40,2,  41,4)

#define DECL_GROUP(L1,L2,NP,P0,L30,P1,L31,P2,L32) \
  static constexpr GTab G_##L1##_##L2 = \
    merge_group(NP, &CGT_##P0, L30, &CGT_##P1, L31, &CGT_##P2, L32);
GROUPS_X(DECL_GROUP)
#undef DECL_GROUP

// Spherical-harmonic normalization constants (incl. sqrt(2) for m>0).
static constexpr float K00=(float)cg::Kd(0,0);
static constexpr float K10=(float)cg::Kd(1,0), K11=(float)cg::Kd(1,1);
static constexpr float K20=(float)cg::Kd(2,0), K21=(float)cg::Kd(2,1), K22=(float)cg::Kd(2,2);
static constexpr float K30=(float)cg::Kd(3,0), K31=(float)cg::Kd(3,1), K32=(float)cg::Kd(3,2), K33=(float)cg::Kd(3,3);
static constexpr float K40=(float)cg::Kd(4,0), K41=(float)cg::Kd(4,1), K42=(float)cg::Kd(4,2), K43=(float)cg::Kd(4,3), K44=(float)cg::Kd(4,4);

static constexpr float PI_F = 3.14159274101257324f; // float32(pi)

// One group-contraction, scalar, fully unrolled & const-folded.
// Product sharing: each (i,j) product computed once (np flag), reused for all
// paths of this (l1,l2) group; ft flag turns the first accumulate into an
// assignment (no zero-init pass needed except never-touched slots).
#define RUN_GROUP(GN,L1,L2,NP,P0,L30,P1,L31,P2,L32,S1,S2,DST,WEX) { \
    float part[GN.ptot]; \
    _Pragma("unroll") \
    for (int k = 0; k < GN.ptot; ++k) if ((GN.zmask >> k) & 1u) part[k] = 0.f; \
    float prod = 0.f; \
    _Pragma("unroll") \
    for (int t = 0; t < GN.n; ++t) { \
      if (GN.np[t]) prod = S1[(L1)*(L1)+(int)GN.i8[t]] * S2[(L2)*(L2)+(int)GN.j8[t]]; \
      if (GN.ft[t]) part[GN.kk[t]]  = GN.v[t] * prod; \
      else          part[GN.kk[t]] += GN.v[t] * prod; \
    } \
    { const float wp = WEX(P0); \
      _Pragma("unroll") for (int k = 0; k < 2*(L30)+1; ++k) \
        DST[(L30)*(L30)+k] += wp * part[k]; } \
    if constexpr ((NP) > 1) { const float wp = WEX(P1); \
      _Pragma("unroll") for (int k = 0; k < 2*(L31)+1; ++k) \
        DST[(L31)*(L31)+k] += wp * part[2*(L30)+1 + k]; } \
    if constexpr ((NP) > 2) { const float wp = WEX(P2); \
      _Pragma("unroll") for (int k = 0; k < 2*(L32)+1; ++k) \
        DST[(L32)*(L32)+k] += wp * part[2*(L30)+1 + 2*(L31)+1 + k]; } \
  }

#define TP1W(P) (W1[(P)*16 + f])
#define TP2W(P) (s * W2[(P)*16 + f])

#define TP1_G(L1,L2,NP,P0,L30,P1,L31,P2,L32) \
  RUN_GROUP(G_##L1##_##L2, L1,L2,NP,P0,L30,P1,L31,P2,L32, a1,a2,y,TP1W)
#define TP2_G(L1,L2,NP,P0,L30,P1,L31,P2,L32) \
  RUN_GROUP(G_##L1##_##L2, L1,L2,NP,P0,L30,P1,L31,P2,L32, y,Ys,o,TP2W)

// One thread per (edge, feature) — the round-1 structure that saturated VALU
// issue — with grouped product-sharing tables (~4300 inst/thread vs ~7400).
// Scalar fp32 only: v_pk_fma_f32 does NOT raise fp32 FLOP rate on gfx950
// (peak 157.3 TF is the scalar-FMA rate), and v2f doubled the spill footprint
// (r3/r4: occupancy 21%, VALUBusy 45%). No occupancy attributes.
__global__ __launch_bounds__(256) void bctmd_kernel(
    const float* __restrict__ A,    // (N,1,25,16)
    const float* __restrict__ D,    // (E,3)
    const float* __restrict__ W1,   // (42,16)
    const float* __restrict__ W2,   // (42,16)
    const int*   __restrict__ NI,   // (E,)
    const int*   __restrict__ NJ,   // (E,)
    float* __restrict__ out,        // (E,1,25,16)
    int E)
{
  int g = blockIdx.x * 256 + threadIdx.x;
  int e = g >> 4;
  int f = g & 15;
  if (e >= E) return;

  const float* __restrict__ a1p = A + (size_t)NI[e] * 400 + f;
  const float* __restrict__ a2p = A + (size_t)NJ[e] * 400 + f;

  float a1[25], a2[25];
#pragma unroll
  for (int i = 0; i < 25; ++i) a1[i] = a1p[i*16];
#pragma unroll
  for (int i = 0; i < 25; ++i) a2[i] = a2p[i*16];

  // ---- TP1: y[k] = sum_p w1[p] * sum_{ij} cg_p[i,j,k] a1[i] a2[j]
  float y[25];
#pragma unroll
  for (int i = 0; i < 25; ++i) y[i] = 0.f;
  GROUPS_X(TP1_G)

  // ---- bond basis: Y_sph(25), radial sinc (this feature), cutoff
  float dx = D[3*e], dy = D[3*e+1], dz = D[3*e+2];
  float r2 = dx*dx + dy*dy + dz*dz + 1e-12f;
  float inv = __builtin_amdgcn_rsqf(r2);
  float r   = r2 * inv;
  float ux = dx*inv, uy = dy*inv, uz = dz*inv;

  float Ys[25];
  {
    float C1 = ux,            S1 = uy;
    float C2 = ux*C1 - uy*S1, S2 = ux*S1 + uy*C1;
    float C3 = ux*C2 - uy*S2, S3 = ux*S2 + uy*C2;
    float C4 = ux*C3 - uy*S3, S4 = ux*S3 + uy*C3;
    float z = uz;
    float Q00 = 1.f;
    float Q11 = 1.f, Q22 = 3.f, Q33 = 15.f, Q44 = 105.f;
    float Q10 = z, Q21 = 3.f*z, Q32 = 15.f*z, Q43 = 105.f*z;
    float Q20 = 0.5f*(3.f*z*Q10 - Q00);
    float Q31 = 0.5f*(5.f*z*Q21 - 3.f*Q11);
    float Q42 = 0.5f*(7.f*z*Q32 - 5.f*Q22);
    float Q30 = (5.f*z*Q20 - 2.f*Q10)*(1.f/3.f);
    float Q41 = (7.f*z*Q31 - 4.f*Q21)*(1.f/3.f);
    float Q40 = 0.25f*(7.f*z*Q30 - 3.f*Q20);

    Ys[0]  = K00*Q00;
    Ys[1]  = K11*Q11*S1;  Ys[2]  = K10*Q10;     Ys[3]  = K11*Q11*C1;
    Ys[4]  = K22*Q22*S2;  Ys[5]  = K21*Q21*S1;  Ys[6]  = K20*Q20;
    Ys[7]  = K21*Q21*C1;  Ys[8]  = K22*Q22*C2;
    Ys[9]  = K33*Q33*S3;  Ys[10] = K32*Q32*S2;  Ys[11] = K31*Q31*S1;
    Ys[12] = K30*Q30;     Ys[13] = K31*Q31*C1;  Ys[14] = K32*Q32*C2;
    Ys[15] = K33*Q33*C3;
    Ys[16] = K44*Q44*S4;  Ys[17] = K43*Q43*S3;  Ys[18] = K42*Q42*S2;
    Ys[19] = K41*Q41*S1;  Ys[20] = K40*Q40;     Ys[21] = K41*Q41*C1;
    Ys[22] = K42*Q42*C2;  Ys[23] = K43*Q43*C3;  Ys[24] = K44*Q44*C4;
  }

  // radial sinc for this feature (k = f+1), cosine cutoff.
  float base = PI_F * r * 0.2f;
  float tt  = base * (float)(f+1);
  float rad = __sinf(tt) * __builtin_amdgcn_rcpf(tt);
  float cut = (r < 5.0f) ? 0.5f*(1.0f + __cosf(base)) : 0.0f;
  float s   = rad * cut;   // folded into the per-path weight in TP2W

  // ---- TP2: out[k] = sum_p (w2[p]*rad*cut) * sum_{ij} cg_p[i,j,k] y[i] Ys[j]
  float o[25];
#pragma unroll
  for (int i = 0; i < 25; ++i) o[i] = 0.f;
  GROUPS_X(TP2_G)

  float* __restrict__ op = out + (size_t)e * 400 + f;
#pragma unroll
  for (int k = 0; k < 25; ++k) op[k*16] = o[k];
}

extern "C" void kernel_launch(void* const* d_in, const int* in_sizes, int n_in,
                              void* d_out, int out_size, void* d_ws, size_t ws_size,
                              hipStream_t stream) {
  const float* A  = (const float*)d_in[0];
  const float* D  = (const float*)d_in[1];
  const float* W1 = (const float*)d_in[2];
  const float* W2 = (const float*)d_in[3];
  const int*   NI = (const int*)d_in[4];
  const int*   NJ = (const int*)d_in[5];
  float* out = (float*)d_out;

  int E = in_sizes[4];
  long total = (long)E * 16;
  int block = 256;
  int grid = (int)((total + block - 1) / block);
  bctmd_kernel<<<grid, block, 0, stream>>>(A, D, W1, W2, NI, NJ, out, E);
}

// Round 6
// 199.865 us; speedup vs baseline: 1.4286x; 1.0765x over previous
//
#include <hip/hip_runtime.h>

// ==========================================================================
// Compile-time Clebsch-Gordan (real basis) table generation.
// Mirrors the reference Python exactly: _cg_complex, _u_matrix, _real_cg.
// ==========================================================================
namespace cg {

constexpr double FACT[16] = {
  1.0, 1.0, 2.0, 6.0, 24.0, 120.0, 720.0, 5040.0, 40320.0, 362880.0,
  3628800.0, 39916800.0, 479001600.0, 6227020800.0, 87178291200.0,
  1307674368000.0 };

constexpr double csqrt_(double x){
  if (x <= 0.0) return 0.0;
  double xx = x, g = 1.0;
  while (xx >= 256.0)      { xx *= (1.0/256.0); g *= 16.0;       }
  while (xx >= 4.0)        { xx *= 0.25;        g *= 2.0;        }
  while (xx < (1.0/256.0)) { xx *= 256.0;       g *= (1.0/16.0); }
  while (xx < 1.0)         { xx *= 4.0;         g *= 0.5;        }
  double s = 1.5;
  for (int i = 0; i < 10; ++i) s = 0.5*(s + xx/s);
  return g*s;
}

constexpr double cg_complex(int j1,int m1,int j2,int m2,int j3,int m3){
  if (m1+m2 != m3) return 0.0;
  int dj = j1-j2; if (dj < 0) dj = -dj;
  if (j3 < dj || j3 > j1+j2) return 0.0;
  if (m1<-j1||m1>j1||m2<-j2||m2>j2||m3<-j3||m3>j3) return 0.0;
  double pre = csqrt_((2.0*j3+1.0)*FACT[j1+j2-j3]*FACT[j1-j2+j3]*FACT[-j1+j2+j3]/FACT[j1+j2+j3+1]);
  pre *= csqrt_(FACT[j1+m1]*FACT[j1-m1]*FACT[j2+m2]*FACT[j2-m2]*FACT[j3+m3]*FACT[j3-m3]);
  double s = 0.0;
  for (int k = 0; k <= j1+j2+j3; ++k){
    int t1=j1+j2-j3-k, t2=j1-m1-k, t3=j2+m2-k, t4=j3-j2+m1+k, t5=j3-j1-m2+k;
    if (t1<0||t2<0||t3<0||t4<0||t5<0) continue;
    double term = 1.0/(FACT[k]*FACT[t1]*FACT[t2]*FACT[t3]*FACT[t4]*FACT[t5]);
    s += (k & 1) ? -term : term;
  }
  return pre*s;
}

struct URow { int n; int col[2]; double re[2]; double im[2]; };

constexpr URow urow(int l, int a){
  URow r{};
  const double is2 = 0.70710678118654752440;
  int m = a - l;
  if (m == 0){
    r.n = 1; r.col[0] = l; r.re[0] = 1.0; r.im[0] = 0.0;
  } else if (m > 0){
    r.n = 2;
    r.col[0] = l+m; r.re[0] = (m & 1) ? -is2 : is2; r.im[0] = 0.0;
    r.col[1] = l-m; r.re[1] = is2;                  r.im[1] = 0.0;
  } else {
    int mm = -m; r.n = 2;
    r.col[0] = l-mm; r.re[0] = 0.0; r.im[0] = is2;                   //  i/sqrt2
    r.col[1] = l+mm; r.re[1] = 0.0; r.im[1] = (mm & 1) ? is2 : -is2; // -i*(-1)^m/sqrt2
  }
  return r;
}

struct PTab {
  int nnz;
  unsigned char ia[192];
  unsigned char jb[192];
  unsigned char kc[192];
  float v[192];
};

constexpr PTab build_path(int l1, int l2, int l3){
  double Cc[9][9] = {};
  for (int i = 0; i < 2*l1+1; ++i)
    for (int j = 0; j < 2*l2+1; ++j){
      int m3 = (i-l1)+(j-l2);
      Cc[i][j] = (m3 >= -l3 && m3 <= l3)
               ? cg_complex(l1, i-l1, l2, j-l2, l3, m3) : 0.0;
    }
  PTab t{};
  for (int a = 0; a < 2*l1+1; ++a)
    for (int b = 0; b < 2*l2+1; ++b)
      for (int c = 0; c < 2*l3+1; ++c){
        URow ra = urow(l1,a), rb = urow(l2,b), rc = urow(l3,c);
        double re = 0.0;
        for (int x = 0; x < ra.n; ++x)
          for (int yy = 0; yy < rb.n; ++yy){
            double pr = ra.re[x]*rb.re[yy] - ra.im[x]*rb.im[yy];
            double pi = ra.re[x]*rb.im[yy] + ra.im[x]*rb.re[yy];
            for (int z = 0; z < rc.n; ++z){
              if (rc.col[z]-l3 != (ra.col[x]-l1)+(rb.col[yy]-l2)) continue;
              double ure = pr*rc.re[z] + pi*rc.im[z];
              re += ure * Cc[ra.col[x]][rb.col[yy]];
            }
          }
        if (re > 1e-10 || re < -1e-10){
          t.ia[t.nnz] = (unsigned char)a;
          t.jb[t.nnz] = (unsigned char)b;
          t.kc[t.nnz] = (unsigned char)c;
          t.v[t.nnz]  = (float)re;
          t.nnz++;
        }
      }
  return t;
}

constexpr double PI_D = 3.14159265358979323846264338327950288;
constexpr double Kd(int l, int m){
  double v = csqrt_((2.0*l+1.0)/(4.0*PI_D)*FACT[l-m]/FACT[l+m]);
  if (m) v *= csqrt_(2.0);
  return v;
}

} // namespace cg

// Path list (p, l1, l2, l3) — must match the Python CG_PATHS iteration order.
#define PATHS_X(X) \
  X(0,0,0,0) X(1,0,1,1) X(2,0,2,2) X(3,0,3,3) X(4,0,4,4) \
  X(5,1,0,1) X(6,1,1,0) X(7,1,1,2) X(8,1,2,1) X(9,1,2,3) X(10,1,3,2) X(11,1,3,4) X(12,1,4,3) \
  X(13,2,0,2) X(14,2,1,1) X(15,2,1,3) X(16,2,2,0) X(17,2,2,2) X(18,2,2,4) X(19,2,3,1) X(20,2,3,3) X(21,2,4,2) X(22,2,4,4) \
  X(23,3,0,3) X(24,3,1,2) X(25,3,1,4) X(26,3,2,1) X(27,3,2,3) X(28,3,3,0) X(29,3,3,2) X(30,3,3,4) X(31,3,4,1) X(32,3,4,3) \
  X(33,4,0,4) X(34,4,1,3) X(35,4,2,2) X(36,4,2,4) X(37,4,3,1) X(38,4,3,3) X(39,4,4,0) X(40,4,4,2) X(41,4,4,4)

#define DECL_TAB(P,L1,L2,L3) static constexpr cg::PTab CGT_##P = cg::build_path(L1,L2,L3);
PATHS_X(DECL_TAB)
#undef DECL_TAB

// ==========================================================================
// Group tables: all paths sharing (l1,l2) merged, nnz sorted by (j,i) so the
// product a1[i]*a2[j] is computed once and reused across paths/outputs.
// np[t]: entry starts a new (i,j) product. ft[t]: first write to part[kk].
// ==========================================================================
struct GTab {
  int n;
  int ptot;
  unsigned int zmask;              // part indices never touched (safety)
  unsigned char i8[512], j8[512], kk[512];
  bool np[512], ft[512];
  float v[512];
};

constexpr GTab merge_group(int npaths,
                           const cg::PTab* t0, int l30,
                           const cg::PTab* t1, int l31,
                           const cg::PTab* t2, int l32){
  GTab g{};
  const cg::PTab* ts[3] = {t0, t1, t2};
  int ls[3] = {l30, l31, l32};
  int pofs[3] = {0,0,0};
  int acc = 0;
  for (int s = 0; s < npaths; ++s){ pofs[s] = acc; acc += 2*ls[s]+1; }
  g.ptot = acc;
  bool touched[32] = {};
  for (int j = 0; j < 9; ++j)
    for (int i = 0; i < 9; ++i){
      bool first = true;
      for (int s = 0; s < npaths; ++s){
        const cg::PTab* T = ts[s];
        for (int t = 0; t < T->nnz; ++t){
          if ((int)T->ia[t] == i && (int)T->jb[t] == j){
            int kx = pofs[s] + (int)T->kc[t];
            g.i8[g.n] = (unsigned char)i;
            g.j8[g.n] = (unsigned char)j;
            g.kk[g.n] = (unsigned char)kx;
            g.np[g.n] = first; first = false;
            g.ft[g.n] = !touched[kx]; touched[kx] = true;
            g.v[g.n]  = T->v[t];
            g.n++;
          }
        }
      }
    }
  unsigned int zm = 0;
  for (int k = 0; k < g.ptot; ++k) if (!touched[k]) zm |= (1u << k);
  g.zmask = zm;
  return g;
}

// Groups: X(L1,L2, NP, P0,L30, P1,L31, P2,L32)  (unused slots repeat P0)
#define GROUPS_X(X) \
  X(0,0, 1,  0,0,   0,0,   0,0) \
  X(0,1, 1,  1,1,   1,1,   1,1) \
  X(0,2, 1,  2,2,   2,2,   2,2) \
  X(0,3, 1,  3,3,   3,3,   3,3) \
  X(0,4, 1,  4,4,   4,4,   4,4) \
  X(1,0, 1,  5,1,   5,1,   5,1) \
  X(1,1, 2,  6,0,   7,2,   7,2) \
  X(1,2, 2,  8,1,   9,3,   9,3) \
  X(1,3, 2, 10,2,  11,4,  11,4) \
  X(1,4, 1, 12,3,  12,3,  12,3) \
  X(2,0, 1, 13,2,  13,2,  13,2) \
  X(2,1, 2, 14,1,  15,3,  15,3) \
  X(2,2, 3, 16,0,  17,2,  18,4) \
  X(2,3, 2, 19,1,  20,3,  20,3) \
  X(2,4, 2, 21,2,  22,4,  22,4) \
  X(3,0, 1, 23,3,  23,3,  23,3) \
  X(3,1, 2, 24,2,  25,4,  25,4) \
  X(3,2, 2, 26,1,  27,3,  27,3) \
  X(3,3, 3, 28,0,  29,2,  30,4) \
  X(3,4, 2, 31,1,  32,3,  32,3) \
  X(4,0, 1, 33,4,  33,4,  33,4) \
  X(4,1, 1, 34,3,  34,3,  34,3) \
  X(4,2, 2, 35,2,  36,4,  36,4) \
  X(4,3, 2, 37,1,  38,3,  38,3) \
  X(4,4, 3, 39,0,  40,2,  41,4)

#define DECL_GROUP(L1,L2,NP,P0,L30,P1,L31,P2,L32) \
  static constexpr GTab G_##L1##_##L2 = \
    merge_group(NP, &CGT_##P0, L30, &CGT_##P1, L31, &CGT_##P2, L32);
GROUPS_X(DECL_GROUP)
#undef DECL_GROUP

// Spherical-harmonic normalization constants (incl. sqrt(2) for m>0).
static constexpr float K00=(float)cg::Kd(0,0);
static constexpr float K10=(float)cg::Kd(1,0), K11=(float)cg::Kd(1,1);
static constexpr float K20=(float)cg::Kd(2,0), K21=(float)cg::Kd(2,1), K22=(float)cg::Kd(2,2);
static constexpr float K30=(float)cg::Kd(3,0), K31=(float)cg::Kd(3,1), K32=(float)cg::Kd(3,2), K33=(float)cg::Kd(3,3);
static constexpr float K40=(float)cg::Kd(4,0), K41=(float)cg::Kd(4,1), K42=(float)cg::Kd(4,2), K43=(float)cg::Kd(4,3), K44=(float)cg::Kd(4,4);

static constexpr float PI_F = 3.14159274101257324f; // float32(pi)

// One group-contraction, scalar, fully unrolled & const-folded.
#define RUN_GROUP(GN,L1,L2,NP,P0,L30,P1,L31,P2,L32,S1,S2,DST,WEX) { \
    float part[GN.ptot]; \
    _Pragma("unroll") \
    for (int k = 0; k < GN.ptot; ++k) if ((GN.zmask >> k) & 1u) part[k] = 0.f; \
    float prod = 0.f; \
    _Pragma("unroll") \
    for (int t = 0; t < GN.n; ++t) { \
      if (GN.np[t]) prod = S1[(L1)*(L1)+(int)GN.i8[t]] * S2[(L2)*(L2)+(int)GN.j8[t]]; \
      if (GN.ft[t]) part[GN.kk[t]]  = GN.v[t] * prod; \
      else          part[GN.kk[t]] += GN.v[t] * prod; \
    } \
    { const float wp = WEX(P0); \
      _Pragma("unroll") for (int k = 0; k < 2*(L30)+1; ++k) \
        DST[(L30)*(L30)+k] += wp * part[k]; } \
    if constexpr ((NP) > 1) { const float wp = WEX(P1); \
      _Pragma("unroll") for (int k = 0; k < 2*(L31)+1; ++k) \
        DST[(L31)*(L31)+k] += wp * part[2*(L30)+1 + k]; } \
    if constexpr ((NP) > 2) { const float wp = WEX(P2); \
      _Pragma("unroll") for (int k = 0; k < 2*(L32)+1; ++k) \
        DST[(L32)*(L32)+k] += wp * part[2*(L30)+1 + 2*(L31)+1 + k]; } \
  }

#define TP1W(P) (W1[(P)*16 + f])
#define TP2W(P) (s * W2[(P)*16 + f])

#define TP1_G(L1,L2,NP,P0,L30,P1,L31,P2,L32) \
  RUN_GROUP(G_##L1##_##L2, L1,L2,NP,P0,L30,P1,L31,P2,L32, a1,a2,y,TP1W)
#define TP2_G(L1,L2,NP,P0,L30,P1,L31,P2,L32) \
  RUN_GROUP(G_##L1##_##L2, L1,L2,NP,P0,L30,P1,L31,P2,L32, y,Ys,o,TP2W)

// One thread per (edge, feature), scalar fp32 (r5 structure), plus
// amdgpu_waves_per_eu(4,4): clamping MAX waves/EU to 4 tells the register
// allocator that occupancy cannot exceed 4/EU, so VGPRs up to 128 are free
// -> it should keep the ~90-float working set resident instead of spilling
// (r5: VGPR=56 with spills; achieved occupancy was only ~3.4 waves/EU anyway,
// so the 4/EU cap does not reduce achieved parallelism). This is the clean
// single-variable version of the r3 experiment (whose regression was caused
// by the v2f working-set doubling, not the waves_per_eu mechanism).
__global__ __launch_bounds__(256)
__attribute__((amdgpu_waves_per_eu(4, 4)))
void bctmd_kernel(
    const float* __restrict__ A,    // (N,1,25,16)
    const float* __restrict__ D,    // (E,3)
    const float* __restrict__ W1,   // (42,16)
    const float* __restrict__ W2,   // (42,16)
    const int*   __restrict__ NI,   // (E,)
    const int*   __restrict__ NJ,   // (E,)
    float* __restrict__ out,        // (E,1,25,16)
    int E)
{
  int g = blockIdx.x * 256 + threadIdx.x;
  int e = g >> 4;
  int f = g & 15;
  if (e >= E) return;

  const float* __restrict__ a1p = A + (size_t)NI[e] * 400 + f;
  const float* __restrict__ a2p = A + (size_t)NJ[e] * 400 + f;

  float a1[25], a2[25];
#pragma unroll
  for (int i = 0; i < 25; ++i) a1[i] = a1p[i*16];
#pragma unroll
  for (int i = 0; i < 25; ++i) a2[i] = a2p[i*16];

  // ---- TP1: y[k] = sum_p w1[p] * sum_{ij} cg_p[i,j,k] a1[i] a2[j]
  float y[25];
#pragma unroll
  for (int i = 0; i < 25; ++i) y[i] = 0.f;
  GROUPS_X(TP1_G)

  // ---- bond basis: Y_sph(25), radial sinc (this feature), cutoff
  float dx = D[3*e], dy = D[3*e+1], dz = D[3*e+2];
  float r2 = dx*dx + dy*dy + dz*dz + 1e-12f;
  float inv = __builtin_amdgcn_rsqf(r2);
  float r   = r2 * inv;
  float ux = dx*inv, uy = dy*inv, uz = dz*inv;

  float Ys[25];
  {
    float C1 = ux,            S1 = uy;
    float C2 = ux*C1 - uy*S1, S2 = ux*S1 + uy*C1;
    float C3 = ux*C2 - uy*S2, S3 = ux*S2 + uy*C2;
    float C4 = ux*C3 - uy*S3, S4 = ux*S3 + uy*C3;
    float z = uz;
    float Q00 = 1.f;
    float Q11 = 1.f, Q22 = 3.f, Q33 = 15.f, Q44 = 105.f;
    float Q10 = z, Q21 = 3.f*z, Q32 = 15.f*z, Q43 = 105.f*z;
    float Q20 = 0.5f*(3.f*z*Q10 - Q00);
    float Q31 = 0.5f*(5.f*z*Q21 - 3.f*Q11);
    float Q42 = 0.5f*(7.f*z*Q32 - 5.f*Q22);
    float Q30 = (5.f*z*Q20 - 2.f*Q10)*(1.f/3.f);
    float Q41 = (7.f*z*Q31 - 4.f*Q21)*(1.f/3.f);
    float Q40 = 0.25f*(7.f*z*Q30 - 3.f*Q20);

    Ys[0]  = K00*Q00;
    Ys[1]  = K11*Q11*S1;  Ys[2]  = K10*Q10;     Ys[3]  = K11*Q11*C1;
    Ys[4]  = K22*Q22*S2;  Ys[5]  = K21*Q21*S1;  Ys[6]  = K20*Q20;
    Ys[7]  = K21*Q21*C1;  Ys[8]  = K22*Q22*C2;
    Ys[9]  = K33*Q33*S3;  Ys[10] = K32*Q32*S2;  Ys[11] = K31*Q31*S1;
    Ys[12] = K30*Q30;     Ys[13] = K31*Q31*C1;  Ys[14] = K32*Q32*C2;
    Ys[15] = K33*Q33*C3;
    Ys[16] = K44*Q44*S4;  Ys[17] = K43*Q43*S3;  Ys[18] = K42*Q42*S2;
    Ys[19] = K41*Q41*S1;  Ys[20] = K40*Q40;     Ys[21] = K41*Q41*C1;
    Ys[22] = K42*Q42*C2;  Ys[23] = K43*Q43*C3;  Ys[24] = K44*Q44*C4;
  }

  // radial sinc for this feature (k = f+1), cosine cutoff.
  float base = PI_F * r * 0.2f;
  float tt  = base * (float)(f+1);
  float rad = __sinf(tt) * __builtin_amdgcn_rcpf(tt);
  float cut = (r < 5.0f) ? 0.5f*(1.0f + __cosf(base)) : 0.0f;
  float s   = rad * cut;   // folded into the per-path weight in TP2W

  // ---- TP2: out[k] = sum_p (w2[p]*rad*cut) * sum_{ij} cg_p[i,j,k] y[i] Ys[j]
  float o[25];
#pragma unroll
  for (int i = 0; i < 25; ++i) o[i] = 0.f;
  GROUPS_X(TP2_G)

  float* __restrict__ op = out + (size_t)e * 400 + f;
#pragma unroll
  for (int k = 0; k < 25; ++k) op[k*16] = o[k];
}

extern "C" void kernel_launch(void* const* d_in, const int* in_sizes, int n_in,
                              void* d_out, int out_size, void* d_ws, size_t ws_size,
                              hipStream_t stream) {
  const float* A  = (const float*)d_in[0];
  const float* D  = (const float*)d_in[1];
  const float* W1 = (const float*)d_in[2];
  const float* W2 = (const float*)d_in[3];
  const int*   NI = (const int*)d_in[4];
  const int*   NJ = (const int*)d_in[5];
  float* out = (float*)d_out;

  int E = in_sizes[4];
  long total = (long)E * 16;
  int block = 256;
  int grid = (int)((total + block - 1) / block);
  bctmd_kernel<<<grid, block, 0, stream>>>(A, D, W1, W2, NI, NJ, out, E);
}